// Round 4
// baseline (59.459 us; speedup 1.0000x reference)
//
#include <hip/hip_runtime.h>

// DGT forward, collapsed to a binary-tree descent on sign(pred_z[node]).
// f32 fast path; rare f64 recompute when |z_f32| < EPS_TIE (only region where
// f32 sign can disagree with the f64 numpy reference).
//
// Latency-hiding structure: 8-lane groups (8 groups/wave), each group runs
// TWO interleaved sample chains (A,B) -> 16 chains/wave. Both chains' W-row
// loads issue back-to-back each level so FMAs+reduce of one chain cover the
// other's L2 latency. 3-step butterfly reduce per chain.
//
// Shapes: x [65536,256] f32, W_pred [1023,256], b_pred [1023],
//         W_or [16,1024], action_stds [16,1024].
// d_out = [out (65536x16) | std (65536x16)] f32.

#define BATCH   65536
#define IN_DIM  256
#define NLEVEL  10
#define NLEAF   1024
#define OUT_DIM 16
#define EPS_TIE 1e-4f

__device__ __forceinline__ int tree_sign_f64(
    const float4* xq, const float* wrow, float bias, int l)
{
    // Rare exact-sign fallback; group-uniform entry (zz uniform per group).
    double A0 = 0.0, A1 = 0.0, A2 = 0.0, A3 = 0.0;
    #pragma unroll
    for (int k = 0; k < 8; ++k) {
        float4 w = *reinterpret_cast<const float4*>(wrow + k * 32 + l * 4);
        A0 += (double)xq[k].x * (double)w.x;
        A1 += (double)xq[k].y * (double)w.y;
        A2 += (double)xq[k].z * (double)w.z;
        A3 += (double)xq[k].w * (double)w.w;
    }
    double Z = (A0 + A1) + (A2 + A3);
    #pragma unroll
    for (int off = 4; off > 0; off >>= 1)
        Z += __shfl_xor(Z, off, 64);
    Z += (double)bias;
    return (Z < 0.0) ? 1 : 0;
}

// 256 threads = 4 waves; 16 samples/wave -> 64 samples/block, 1024 blocks.
__global__ __launch_bounds__(256, 3) void dgt_kernel(
    const float* __restrict__ x,
    const float* __restrict__ W_pred,
    const float* __restrict__ b_pred,
    const float* __restrict__ W_or,
    const float* __restrict__ a_std,
    float* __restrict__ out)
{
    const int lane = threadIdx.x & 63;
    const int wid  = threadIdx.x >> 6;   // wave in block (0..3)
    const int l    = lane & 7;           // lane within 8-group
    const int g    = lane >> 3;          // group within wave (0..7)
    const int sA   = blockIdx.x * 64 + wid * 16 + g;   // chain A sample
    const int sB   = sA + 8;                           // chain B sample

    // x fragments: elem k*32 + l*4 + c; 128B coalesced per group per k.
    float4 xA[8], xB[8];
    {
        const float* ra = x + (size_t)sA * IN_DIM;
        const float* rb = x + (size_t)sB * IN_DIM;
        #pragma unroll
        for (int k = 0; k < 8; ++k)
            xA[k] = *reinterpret_cast<const float4*>(ra + k * 32 + l * 4);
        #pragma unroll
        for (int k = 0; k < 8; ++k)
            xB[k] = *reinterpret_cast<const float4*>(rb + k * 32 + l * 4);
    }

    int nodeA = 0, posA = 0, nodeB = 0, posB = 0;
    float bA = b_pred[0], bB = bA;

    #pragma unroll
    for (int lvl = 0; lvl < NLEVEL; ++lvl) {
        const float* wrA = W_pred + (size_t)nodeA * IN_DIM;
        const float* wrB = W_pred + (size_t)nodeB * IN_DIM;

        // Issue all 16 row-fragment loads up front (latency overlap).
        float4 wA[8], wB[8];
        #pragma unroll
        for (int k = 0; k < 8; ++k)
            wA[k] = *reinterpret_cast<const float4*>(wrA + k * 32 + l * 4);
        #pragma unroll
        for (int k = 0; k < 8; ++k)
            wB[k] = *reinterpret_cast<const float4*>(wrB + k * 32 + l * 4);

        // 4 independent partials per chain.
        float a0=0.f,a1=0.f,a2=0.f,a3=0.f, c0=0.f,c1=0.f,c2=0.f,c3=0.f;
        #pragma unroll
        for (int k = 0; k < 8; ++k) {
            a0 += xA[k].x * wA[k].x; a1 += xA[k].y * wA[k].y;
            a2 += xA[k].z * wA[k].z; a3 += xA[k].w * wA[k].w;
        }
        #pragma unroll
        for (int k = 0; k < 8; ++k) {
            c0 += xB[k].x * wB[k].x; c1 += xB[k].y * wB[k].y;
            c2 += xB[k].z * wB[k].z; c3 += xB[k].w * wB[k].w;
        }

        // Interleaved 3-step butterflies (A's shuffle hides under B's and
        // vice versa). Bitwise-uniform within each 8-lane group.
        float tA = (a0 + a1) + (a2 + a3);
        float tB = (c0 + c1) + (c2 + c3);
        #pragma unroll
        for (int off = 4; off > 0; off >>= 1) {
            tA += __shfl_xor(tA, off, 64);
            tB += __shfl_xor(tB, off, 64);
        }
        float zA = tA + bA;
        float zB = tB + bB;

        int rightA, rightB;
        if (__builtin_expect(fabsf(zA) >= EPS_TIE, 1))
            rightA = (zA < 0.f) ? 1 : 0;
        else
            rightA = tree_sign_f64(xA, wrA, bA, l);
        if (__builtin_expect(fabsf(zB) >= EPS_TIE, 1))
            rightB = (zB < 0.f) ? 1 : 0;
        else
            rightB = tree_sign_f64(xB, wrB, bB, l);

        posA = 2 * posA + rightA;  nodeA = 2 * nodeA + 1 + rightA;
        posB = 2 * posB + rightB;  nodeB = 2 * nodeB + 1 + rightB;

        if (lvl < NLEVEL - 1) {  // bias of the new current nodes
            bA = b_pred[nodeA];
            bB = b_pred[nodeB];
        }
    }
    const int leafA = posA, leafB = posB;  // in [0, 1024)

    // Epilogue: lane l covers classes {2l, 2l+1}; tables are L2-resident.
    #pragma unroll
    for (int ch = 0; ch < 2; ++ch) {
        const int leaf = ch ? leafB : leafA;
        const int smp  = ch ? sB : sA;
        float zx = W_or[(size_t)(2 * l)     * NLEAF + leaf];
        float zy = W_or[(size_t)(2 * l + 1) * NLEAF + leaf];
        float m = fmaxf(zx, zy);
        #pragma unroll
        for (int off = 4; off > 0; off >>= 1)
            m = fmaxf(m, __shfl_xor(m, off, 64));
        float ex = __expf(zx - m), ey = __expf(zy - m);
        float s = ex + ey;
        #pragma unroll
        for (int off = 4; off > 0; off >>= 1)
            s += __shfl_xor(s, off, 64);
        float2 o = make_float2(ex / s, ey / s);
        *reinterpret_cast<float2*>(out + (size_t)smp * OUT_DIM + 2 * l) = o;

        float dx = a_std[(size_t)(2 * l)     * NLEAF + leaf];
        float dy = a_std[(size_t)(2 * l + 1) * NLEAF + leaf];
        float2 sd = make_float2(fminf(fmaxf(dx, -20.f), 2.f),
                                fminf(fmaxf(dy, -20.f), 2.f));
        *reinterpret_cast<float2*>(out + (size_t)BATCH * OUT_DIM
                                   + (size_t)smp * OUT_DIM + 2 * l) = sd;
    }
}

extern "C" void kernel_launch(void* const* d_in, const int* in_sizes, int n_in,
                              void* d_out, int out_size, void* d_ws, size_t ws_size,
                              hipStream_t stream) {
    const float* x      = (const float*)d_in[0];
    const float* W_pred = (const float*)d_in[1];
    const float* b_pred = (const float*)d_in[2];
    const float* W_or   = (const float*)d_in[3];
    const float* a_std  = (const float*)d_in[4];
    float* out = (float*)d_out;

    hipLaunchKernelGGL(dgt_kernel, dim3(BATCH / 64), dim3(256), 0, stream,
                       x, W_pred, b_pred, W_or, a_std, out);
}

// Round 5
// 52.285 us; speedup vs baseline: 1.1372x; 1.1372x over previous
//
#include <hip/hip_runtime.h>

// DGT forward, collapsed to a binary-tree descent on sign(pred_z[node]).
// R1 geometry (16-lane groups, 4 samples/wave, low VGPR) with:
//  - f32 fast-path dot; f64 recompute only when |z_f32| < EPS_TIE (the only
//    region where the f32 sign can disagree with the f64 numpy reference).
//  - group reduction via DPP (quad_perm xor1/xor2, row_half_mirror,
//    row_mirror): full-rate VALU, and bitwise-uniform across the 16 lanes
//    (involution pairing + commutative add), so branches stay group-uniform.
//
// Shapes: x [65536,256] f32, W_pred [1023,256], b_pred [1023],
//         W_or [16,1024], action_stds [16,1024].
// d_out = [out (65536x16) | std (65536x16)] f32.

#define BATCH   65536
#define IN_DIM  256
#define NLEVEL  10
#define NLEAF   1024
#define OUT_DIM 16
#define EPS_TIE 1e-3f

#define DPP_QUAD_XOR1   0xB1   // quad_perm [1,0,3,2]
#define DPP_QUAD_XOR2   0x4E   // quad_perm [2,3,0,1]
#define DPP_HALF_MIRROR 0x141  // lane l <-> 7-l within each 8 (crosses quads)
#define DPP_MIRROR      0x140  // lane l <-> 15-l within row (crosses halves)

template <int CTRL>
__device__ __forceinline__ float dpp_xfer(float v) {
    return __int_as_float(__builtin_amdgcn_update_dpp(
        0, __float_as_int(v), CTRL, 0xf, 0xf, true));
}

// Sum across the 16-lane group; result bitwise-identical on all 16 lanes.
__device__ __forceinline__ float group16_sum(float v) {
    v += dpp_xfer<DPP_QUAD_XOR1>(v);
    v += dpp_xfer<DPP_QUAD_XOR2>(v);
    v += dpp_xfer<DPP_HALF_MIRROR>(v);
    v += dpp_xfer<DPP_MIRROR>(v);
    return v;
}
__device__ __forceinline__ float group16_max(float v) {
    v = fmaxf(v, dpp_xfer<DPP_QUAD_XOR1>(v));
    v = fmaxf(v, dpp_xfer<DPP_QUAD_XOR2>(v));
    v = fmaxf(v, dpp_xfer<DPP_HALF_MIRROR>(v));
    v = fmaxf(v, dpp_xfer<DPP_MIRROR>(v));
    return v;
}

// Rare exact-sign fallback (group-uniform entry: z is bitwise-uniform).
__device__ __forceinline__ int tree_sign_f64(
    const float4* xq, const float* wrow, float bias, int l)
{
    double A0 = 0.0, A1 = 0.0, A2 = 0.0, A3 = 0.0;
    #pragma unroll
    for (int k = 0; k < 4; ++k) {
        float4 w = *reinterpret_cast<const float4*>(wrow + k * 64 + l * 4);
        A0 += (double)xq[k].x * (double)w.x;
        A1 += (double)xq[k].y * (double)w.y;
        A2 += (double)xq[k].z * (double)w.z;
        A3 += (double)xq[k].w * (double)w.w;
    }
    double Z = (A0 + A1) + (A2 + A3);
    #pragma unroll
    for (int off = 8; off > 0; off >>= 1)       // xor involution: uniform
        Z += __shfl_xor(Z, off, 64);
    Z += (double)bias;
    return (Z < 0.0) ? 1 : 0;
}

// 256 threads = 4 waves; 4 samples/wave -> 16/block, 4096 blocks.
__global__ __launch_bounds__(256, 8) void dgt_kernel(
    const float* __restrict__ x,
    const float* __restrict__ W_pred,
    const float* __restrict__ b_pred,
    const float* __restrict__ W_or,
    const float* __restrict__ a_std,
    float* __restrict__ out)
{
    const int lane = threadIdx.x & 63;
    const int wid  = threadIdx.x >> 6;   // wave in block (0..3)
    const int l    = lane & 15;          // lane within 16-group
    const int g    = lane >> 4;          // group (sample) within wave
    const int sample = (blockIdx.x * 4 + wid) * 4 + g;

    // x fragment: elem k*64 + l*4 + c; 256B coalesced segments per group.
    const float* xrow = x + (size_t)sample * IN_DIM;
    float4 xq[4];
    #pragma unroll
    for (int k = 0; k < 4; ++k)
        xq[k] = *reinterpret_cast<const float4*>(xrow + k * 64 + l * 4);

    int node = 0, pos = 0;
    float bcur = b_pred[0];
    const float* wrow = W_pred;

    #pragma unroll
    for (int lvl = 0; lvl < NLEVEL; ++lvl) {
        // Current node's row fragments (single row, no speculation).
        float4 w0 = *reinterpret_cast<const float4*>(wrow +   0 + l * 4);
        float4 w1 = *reinterpret_cast<const float4*>(wrow +  64 + l * 4);
        float4 w2 = *reinterpret_cast<const float4*>(wrow + 128 + l * 4);
        float4 w3 = *reinterpret_cast<const float4*>(wrow + 192 + l * 4);

        // Children biases ready before the sign resolves (off critical path).
        float bL = 0.f, bR = 0.f;
        if (lvl < NLEVEL - 1) {
            bL = b_pred[2 * node + 1];
            bR = b_pred[2 * node + 2];
        }

        // 4 independent partials, then DPP tree (bitwise-uniform result).
        float a0, a1, a2, a3;
        a0  = xq[0].x * w0.x; a1  = xq[0].y * w0.y;
        a2  = xq[0].z * w0.z; a3  = xq[0].w * w0.w;
        a0 += xq[1].x * w1.x; a1 += xq[1].y * w1.y;
        a2 += xq[1].z * w1.z; a3 += xq[1].w * w1.w;
        a0 += xq[2].x * w2.x; a1 += xq[2].y * w2.y;
        a2 += xq[2].z * w2.z; a3 += xq[2].w * w2.w;
        a0 += xq[3].x * w3.x; a1 += xq[3].y * w3.y;
        a2 += xq[3].z * w3.z; a3 += xq[3].w * w3.w;
        float z = group16_sum((a0 + a1) + (a2 + a3)) + bcur;

        int right;
        if (__builtin_expect(fabsf(z) >= EPS_TIE, 1))
            right = (z < 0.f) ? 1 : 0;
        else
            right = tree_sign_f64(xq, wrow, bcur, l);  // group-uniform entry

        pos  = 2 * pos + right;
        node = 2 * node + 1 + right;
        if (lvl < NLEVEL - 1) {
            bcur = right ? bR : bL;
            wrow = W_pred + (size_t)node * IN_DIM;
        }
    }
    const int leaf = pos;  // in [0, 1024)

    // Epilogue: softmax over 16 classes of W_or[:, leaf]; one class/lane.
    float zc = W_or[l * NLEAF + leaf];
    float m  = group16_max(zc);
    float e  = __expf(zc - m);
    float s  = group16_sum(e);
    // Wave-wide store address = base*16 + lane -> contiguous 256B/wave.
    out[(size_t)sample * OUT_DIM + l] = e / s;

    float sd = a_std[l * NLEAF + leaf];
    sd = fminf(fmaxf(sd, -20.0f), 2.0f);
    out[(size_t)BATCH * OUT_DIM + (size_t)sample * OUT_DIM + l] = sd;
}

extern "C" void kernel_launch(void* const* d_in, const int* in_sizes, int n_in,
                              void* d_out, int out_size, void* d_ws, size_t ws_size,
                              hipStream_t stream) {
    const float* x      = (const float*)d_in[0];
    const float* W_pred = (const float*)d_in[1];
    const float* b_pred = (const float*)d_in[2];
    const float* W_or   = (const float*)d_in[3];
    const float* a_std  = (const float*)d_in[4];
    float* out = (float*)d_out;

    hipLaunchKernelGGL(dgt_kernel, dim3(BATCH / 16), dim3(256), 0, stream,
                       x, W_pred, b_pred, W_or, a_std, out);
}

// Round 6
// 45.810 us; speedup vs baseline: 1.2979x; 1.1413x over previous
//
#include <hip/hip_runtime.h>

// DGT forward, collapsed to a binary-tree descent on sign(pred_z[node]).
// R5 structure (16-lane groups, DPP reduce, f32 fast path + rare f64 tie
// fallback) with the spill fixed:
//  - __launch_bounds__(256,6): ~85-VGPR budget for a ~55-VGPR footprint,
//    6 waves/SIMD. (256,8)'s 64-VGPR cap caused 86 MB of scratch in R5.
//  - x fragment held as FOUR NAMED float4s (never an indexed array) so the
//    allocator can't demote it to scratch (rule: runtime-indexed arrays
//    go to local memory).
//
// Shapes: x [65536,256] f32, W_pred [1023,256], b_pred [1023],
//         W_or [16,1024], action_stds [16,1024].
// d_out = [out (65536x16) | std (65536x16)] f32.

#define BATCH   65536
#define IN_DIM  256
#define NLEVEL  10
#define NLEAF   1024
#define OUT_DIM 16
#define EPS_TIE 1e-3f

#define DPP_QUAD_XOR1   0xB1   // quad_perm [1,0,3,2]
#define DPP_QUAD_XOR2   0x4E   // quad_perm [2,3,0,1]
#define DPP_HALF_MIRROR 0x141  // lane l <-> 7-l within each 8
#define DPP_MIRROR      0x140  // lane l <-> 15-l within row-of-16

template <int CTRL>
__device__ __forceinline__ float dpp_xfer(float v) {
    return __int_as_float(__builtin_amdgcn_update_dpp(
        0, __float_as_int(v), CTRL, 0xf, 0xf, true));
}

// Sum across the 16-lane group; bitwise-identical on all 16 lanes
// (involution pairing + commutative add at every step).
__device__ __forceinline__ float group16_sum(float v) {
    v += dpp_xfer<DPP_QUAD_XOR1>(v);
    v += dpp_xfer<DPP_QUAD_XOR2>(v);
    v += dpp_xfer<DPP_HALF_MIRROR>(v);
    v += dpp_xfer<DPP_MIRROR>(v);
    return v;
}
__device__ __forceinline__ float group16_max(float v) {
    v = fmaxf(v, dpp_xfer<DPP_QUAD_XOR1>(v));
    v = fmaxf(v, dpp_xfer<DPP_QUAD_XOR2>(v));
    v = fmaxf(v, dpp_xfer<DPP_HALF_MIRROR>(v));
    v = fmaxf(v, dpp_xfer<DPP_MIRROR>(v));
    return v;
}

// Rare exact-sign fallback (|z_f32| < EPS_TIE). Group-uniform entry: z is
// bitwise-uniform across the 16-lane group, so shuffle partners are active.
__device__ __forceinline__ int tree_sign_f64(
    float4 x0, float4 x1, float4 x2, float4 x3,
    const float* wrow, float bias, int l)
{
    float4 w0 = *reinterpret_cast<const float4*>(wrow +   0 + l * 4);
    float4 w1 = *reinterpret_cast<const float4*>(wrow +  64 + l * 4);
    float4 w2 = *reinterpret_cast<const float4*>(wrow + 128 + l * 4);
    float4 w3 = *reinterpret_cast<const float4*>(wrow + 192 + l * 4);
    double A0, A1, A2, A3;
    A0  = (double)x0.x * (double)w0.x; A1  = (double)x0.y * (double)w0.y;
    A2  = (double)x0.z * (double)w0.z; A3  = (double)x0.w * (double)w0.w;
    A0 += (double)x1.x * (double)w1.x; A1 += (double)x1.y * (double)w1.y;
    A2 += (double)x1.z * (double)w1.z; A3 += (double)x1.w * (double)w1.w;
    A0 += (double)x2.x * (double)w2.x; A1 += (double)x2.y * (double)w2.y;
    A2 += (double)x2.z * (double)w2.z; A3 += (double)x2.w * (double)w2.w;
    A0 += (double)x3.x * (double)w3.x; A1 += (double)x3.y * (double)w3.y;
    A2 += (double)x3.z * (double)w3.z; A3 += (double)x3.w * (double)w3.w;
    double Z = (A0 + A1) + (A2 + A3);
    #pragma unroll
    for (int off = 8; off > 0; off >>= 1)   // xor involution: uniform result
        Z += __shfl_xor(Z, off, 64);
    Z += (double)bias;
    return (Z < 0.0) ? 1 : 0;
}

// 256 threads = 4 waves; 4 samples/wave -> 16/block, 4096 blocks.
__global__ __launch_bounds__(256, 6) void dgt_kernel(
    const float* __restrict__ x,
    const float* __restrict__ W_pred,
    const float* __restrict__ b_pred,
    const float* __restrict__ W_or,
    const float* __restrict__ a_std,
    float* __restrict__ out)
{
    const int lane = threadIdx.x & 63;
    const int wid  = threadIdx.x >> 6;   // wave in block (0..3)
    const int l    = lane & 15;          // lane within 16-group
    const int g    = lane >> 4;          // group (sample) within wave
    const int sample = (blockIdx.x * 4 + wid) * 4 + g;

    // x fragment: elem k*64 + l*4 + c; 256B coalesced segments per group.
    const float* xrow = x + (size_t)sample * IN_DIM;
    float4 x0 = *reinterpret_cast<const float4*>(xrow +   0 + l * 4);
    float4 x1 = *reinterpret_cast<const float4*>(xrow +  64 + l * 4);
    float4 x2 = *reinterpret_cast<const float4*>(xrow + 128 + l * 4);
    float4 x3 = *reinterpret_cast<const float4*>(xrow + 192 + l * 4);

    int node = 0, pos = 0;
    float bcur = b_pred[0];
    const float* wrow = W_pred;

    #pragma unroll
    for (int lvl = 0; lvl < NLEVEL; ++lvl) {
        float4 w0 = *reinterpret_cast<const float4*>(wrow +   0 + l * 4);
        float4 w1 = *reinterpret_cast<const float4*>(wrow +  64 + l * 4);
        float4 w2 = *reinterpret_cast<const float4*>(wrow + 128 + l * 4);
        float4 w3 = *reinterpret_cast<const float4*>(wrow + 192 + l * 4);

        // Children biases fetched before the sign resolves (off crit path).
        float bL = 0.f, bR = 0.f;
        if (lvl < NLEVEL - 1) {
            bL = b_pred[2 * node + 1];
            bR = b_pred[2 * node + 2];
        }

        // 4 independent partials, then DPP tree (bitwise-uniform result).
        float a0, a1, a2, a3;
        a0  = x0.x * w0.x; a1  = x0.y * w0.y;
        a2  = x0.z * w0.z; a3  = x0.w * w0.w;
        a0 += x1.x * w1.x; a1 += x1.y * w1.y;
        a2 += x1.z * w1.z; a3 += x1.w * w1.w;
        a0 += x2.x * w2.x; a1 += x2.y * w2.y;
        a2 += x2.z * w2.z; a3 += x2.w * w2.w;
        a0 += x3.x * w3.x; a1 += x3.y * w3.y;
        a2 += x3.z * w3.z; a3 += x3.w * w3.w;
        float z = group16_sum((a0 + a1) + (a2 + a3)) + bcur;

        int right;
        if (__builtin_expect(fabsf(z) >= EPS_TIE, 1))
            right = (z < 0.f) ? 1 : 0;
        else
            right = tree_sign_f64(x0, x1, x2, x3, wrow, bcur, l);

        pos  = 2 * pos + right;
        node = 2 * node + 1 + right;
        if (lvl < NLEVEL - 1) {
            bcur = right ? bR : bL;
            wrow = W_pred + (size_t)node * IN_DIM;
        }
    }
    const int leaf = pos;  // in [0, 1024)

    // Epilogue: softmax over 16 classes of W_or[:, leaf]; one class/lane.
    float zc = W_or[l * NLEAF + leaf];
    float m  = group16_max(zc);
    float e  = __expf(zc - m);
    float s  = group16_sum(e);
    // Wave-wide store address = base*16 + lane -> contiguous 256B/wave.
    out[(size_t)sample * OUT_DIM + l] = e / s;

    float sd = a_std[l * NLEAF + leaf];
    sd = fminf(fmaxf(sd, -20.0f), 2.0f);
    out[(size_t)BATCH * OUT_DIM + (size_t)sample * OUT_DIM + l] = sd;
}

extern "C" void kernel_launch(void* const* d_in, const int* in_sizes, int n_in,
                              void* d_out, int out_size, void* d_ws, size_t ws_size,
                              hipStream_t stream) {
    const float* x      = (const float*)d_in[0];
    const float* W_pred = (const float*)d_in[1];
    const float* b_pred = (const float*)d_in[2];
    const float* W_or   = (const float*)d_in[3];
    const float* a_std  = (const float*)d_in[4];
    float* out = (float*)d_out;

    hipLaunchKernelGGL(dgt_kernel, dim3(BATCH / 16), dim3(256), 0, stream,
                       x, W_pred, b_pred, W_or, a_std, out);
}

// Round 7
// 45.445 us; speedup vs baseline: 1.3084x; 1.0080x over previous
//
#include <hip/hip_runtime.h>

// DGT forward, collapsed to a binary-tree descent on sign(pred_z[node]).
// Structure: 8-lane groups (8 samples/wave), f32 fast-path dot with DPP
// group reduce; rare f64 recompute when |z_f32| < EPS_TIE (the only region
// where the f32 sign can disagree with the f64 numpy reference).
//
// Hard-learned rules applied:
//  - __launch_bounds__(256,4) ONLY (R5/R6: higher min-waves hints made the
//    allocator spill ~28B/thread to scratch -> WRITE_SIZE 8MB->37MB, chain
//    gained scratch round-trips). WRITE_SIZE ~8.2MB is the no-spill check.
//  - ALL per-thread state in NAMED float4s (x0..x7, w0..w7): runtime-indexed
//    arrays go to local memory (R2/R4 failure).
//
// Shapes: x [65536,256] f32, W_pred [1023,256], b_pred [1023],
//         W_or [16,1024], action_stds [16,1024].
// d_out = [out (65536x16) | std (65536x16)] f32.

#define BATCH   65536
#define IN_DIM  256
#define NLEVEL  10
#define NLEAF   1024
#define OUT_DIM 16
#define EPS_TIE 1e-3f

#define DPP_QUAD_XOR1   0xB1   // quad_perm [1,0,3,2]  : lane ^1
#define DPP_QUAD_XOR2   0x4E   // quad_perm [2,3,0,1]  : lane ^2
#define DPP_HALF_MIRROR 0x141  // row_half_mirror      : lane l <-> 7-l

template <int CTRL>
__device__ __forceinline__ float dpp_xfer(float v) {
    return __int_as_float(__builtin_amdgcn_update_dpp(
        0, __float_as_int(v), CTRL, 0xf, 0xf, true));
}

// Sum across the 8-lane group; bitwise-identical on all 8 lanes
// (involution pairing + commutative add at every step).
__device__ __forceinline__ float group8_sum(float v) {
    v += dpp_xfer<DPP_QUAD_XOR1>(v);
    v += dpp_xfer<DPP_QUAD_XOR2>(v);
    v += dpp_xfer<DPP_HALF_MIRROR>(v);
    return v;
}
__device__ __forceinline__ float group8_max(float v) {
    v = fmaxf(v, dpp_xfer<DPP_QUAD_XOR1>(v));
    v = fmaxf(v, dpp_xfer<DPP_QUAD_XOR2>(v));
    v = fmaxf(v, dpp_xfer<DPP_HALF_MIRROR>(v));
    return v;
}

// Rare exact-sign fallback (|z_f32| < EPS_TIE). Group-uniform entry: z is
// bitwise-uniform across the 8-lane group, so shuffle partners are active.
__device__ __forceinline__ int tree_sign_f64(
    float4 x0, float4 x1, float4 x2, float4 x3,
    float4 x4, float4 x5, float4 x6, float4 x7,
    const float* wrow, float bias, int l)
{
    double A0 = 0.0, A1 = 0.0, A2 = 0.0, A3 = 0.0;
#define ACC64(K, XV)                                                        \
    {                                                                       \
        float4 w = *reinterpret_cast<const float4*>(wrow + (K)*32 + l * 4); \
        A0 += (double)XV.x * (double)w.x; A1 += (double)XV.y * (double)w.y; \
        A2 += (double)XV.z * (double)w.z; A3 += (double)XV.w * (double)w.w; \
    }
    ACC64(0, x0) ACC64(1, x1) ACC64(2, x2) ACC64(3, x3)
    ACC64(4, x4) ACC64(5, x5) ACC64(6, x6) ACC64(7, x7)
#undef ACC64
    double Z = (A0 + A1) + (A2 + A3);
    #pragma unroll
    for (int off = 4; off > 0; off >>= 1)   // xor involution: uniform result
        Z += __shfl_xor(Z, off, 64);
    Z += (double)bias;
    return (Z < 0.0) ? 1 : 0;
}

// 256 threads = 4 waves; 8 samples/wave -> 32/block, 2048 blocks.
__global__ __launch_bounds__(256, 4) void dgt_kernel(
    const float* __restrict__ x,
    const float* __restrict__ W_pred,
    const float* __restrict__ b_pred,
    const float* __restrict__ W_or,
    const float* __restrict__ a_std,
    float* __restrict__ out)
{
    const int lane = threadIdx.x & 63;
    const int wid  = threadIdx.x >> 6;   // wave in block (0..3)
    const int l    = lane & 7;           // lane within 8-group
    const int g    = lane >> 3;          // group (sample) within wave
    const int sample = blockIdx.x * 32 + wid * 8 + g;

    // x fragment: elem k*32 + l*4 + c; 128B coalesced segments per group.
    const float* xrow = x + (size_t)sample * IN_DIM;
    float4 x0 = *reinterpret_cast<const float4*>(xrow +   0 + l * 4);
    float4 x1 = *reinterpret_cast<const float4*>(xrow +  32 + l * 4);
    float4 x2 = *reinterpret_cast<const float4*>(xrow +  64 + l * 4);
    float4 x3 = *reinterpret_cast<const float4*>(xrow +  96 + l * 4);
    float4 x4 = *reinterpret_cast<const float4*>(xrow + 128 + l * 4);
    float4 x5 = *reinterpret_cast<const float4*>(xrow + 160 + l * 4);
    float4 x6 = *reinterpret_cast<const float4*>(xrow + 192 + l * 4);
    float4 x7 = *reinterpret_cast<const float4*>(xrow + 224 + l * 4);

    int node = 0, pos = 0;
    float bcur = b_pred[0];
    const float* wrow = W_pred;

    #pragma unroll
    for (int lvl = 0; lvl < NLEVEL; ++lvl) {
        // All 8 row-fragment loads issued up front: one vmcnt covers them.
        float4 w0 = *reinterpret_cast<const float4*>(wrow +   0 + l * 4);
        float4 w1 = *reinterpret_cast<const float4*>(wrow +  32 + l * 4);
        float4 w2 = *reinterpret_cast<const float4*>(wrow +  64 + l * 4);
        float4 w3 = *reinterpret_cast<const float4*>(wrow +  96 + l * 4);
        float4 w4 = *reinterpret_cast<const float4*>(wrow + 128 + l * 4);
        float4 w5 = *reinterpret_cast<const float4*>(wrow + 160 + l * 4);
        float4 w6 = *reinterpret_cast<const float4*>(wrow + 192 + l * 4);
        float4 w7 = *reinterpret_cast<const float4*>(wrow + 224 + l * 4);

        // Children biases fetched before the sign resolves (off crit path).
        float bL = 0.f, bR = 0.f;
        if (lvl < NLEVEL - 1) {
            bL = b_pred[2 * node + 1];
            bR = b_pred[2 * node + 2];
        }

        // 4 independent partials (8-deep dependent FMA chains each).
        float a0, a1, a2, a3;
        a0  = x0.x * w0.x; a1  = x0.y * w0.y; a2  = x0.z * w0.z; a3  = x0.w * w0.w;
        a0 += x1.x * w1.x; a1 += x1.y * w1.y; a2 += x1.z * w1.z; a3 += x1.w * w1.w;
        a0 += x2.x * w2.x; a1 += x2.y * w2.y; a2 += x2.z * w2.z; a3 += x2.w * w2.w;
        a0 += x3.x * w3.x; a1 += x3.y * w3.y; a2 += x3.z * w3.z; a3 += x3.w * w3.w;
        a0 += x4.x * w4.x; a1 += x4.y * w4.y; a2 += x4.z * w4.z; a3 += x4.w * w4.w;
        a0 += x5.x * w5.x; a1 += x5.y * w5.y; a2 += x5.z * w5.z; a3 += x5.w * w5.w;
        a0 += x6.x * w6.x; a1 += x6.y * w6.y; a2 += x6.z * w6.z; a3 += x6.w * w6.w;
        a0 += x7.x * w7.x; a1 += x7.y * w7.y; a2 += x7.z * w7.z; a3 += x7.w * w7.w;
        float z = group8_sum((a0 + a1) + (a2 + a3)) + bcur;

        int right;
        if (__builtin_expect(fabsf(z) >= EPS_TIE, 1))
            right = (z < 0.f) ? 1 : 0;
        else
            right = tree_sign_f64(x0, x1, x2, x3, x4, x5, x6, x7,
                                  wrow, bcur, l);   // group-uniform entry

        pos  = 2 * pos + right;
        node = 2 * node + 1 + right;
        if (lvl < NLEVEL - 1) {
            bcur = right ? bR : bL;
            wrow = W_pred + (size_t)node * IN_DIM;
        }
    }
    const int leaf = pos;  // in [0, 1024)

    // Epilogue: lane l covers classes {2l, 2l+1}; tables are L2-resident.
    float zx = W_or[(size_t)(2 * l)     * NLEAF + leaf];
    float zy = W_or[(size_t)(2 * l + 1) * NLEAF + leaf];
    float m  = group8_max(fmaxf(zx, zy));
    float ex = __expf(zx - m), ey = __expf(zy - m);
    float s  = group8_sum(ex + ey);
    // Per wave: addresses (base+g)*64B + l*8B -> contiguous 512B.
    *reinterpret_cast<float2*>(out + (size_t)sample * OUT_DIM + 2 * l) =
        make_float2(ex / s, ey / s);

    float dx = a_std[(size_t)(2 * l)     * NLEAF + leaf];
    float dy = a_std[(size_t)(2 * l + 1) * NLEAF + leaf];
    *reinterpret_cast<float2*>(out + (size_t)BATCH * OUT_DIM
                               + (size_t)sample * OUT_DIM + 2 * l) =
        make_float2(fminf(fmaxf(dx, -20.f), 2.f),
                    fminf(fmaxf(dy, -20.f), 2.f));
}

extern "C" void kernel_launch(void* const* d_in, const int* in_sizes, int n_in,
                              void* d_out, int out_size, void* d_ws, size_t ws_size,
                              hipStream_t stream) {
    const float* x      = (const float*)d_in[0];
    const float* W_pred = (const float*)d_in[1];
    const float* b_pred = (const float*)d_in[2];
    const float* W_or   = (const float*)d_in[3];
    const float* a_std  = (const float*)d_in[4];
    float* out = (float*)d_out;

    hipLaunchKernelGGL(dgt_kernel, dim3(BATCH / 32), dim3(256), 0, stream,
                       x, W_pred, b_pred, W_or, a_std, out);
}

// Round 8
// 37.218 us; speedup vs baseline: 1.5976x; 1.2210x over previous
//
#include <hip/hip_runtime.h>

// DGT forward, collapsed to a binary-tree descent on sign(pred_z[node]).
// Structure (= R7): 8-lane groups (8 samples/wave), f32 fast-path dot with
// 3-step DPP group reduce; rare f64 recompute when |z_f32| < EPS_TIE (the
// only region where the f32 sign can disagree with the f64 numpy reference).
//
// Hard-learned rules:
//  - hipcc budgets VGPRs as 256/min_waves from __launch_bounds__'s 2nd arg
//    (measured: (256,8)->32, (256,6)->40, (256,4)->64, (256,3)->84).
//    This kernel's footprint is ~90 VGPR -> use (256,2) for a 128 cap.
//    Spill signature to check: WRITE_SIZE must be ~8.2MB (output only).
//  - ALL per-thread state in NAMED float4s: runtime-indexed arrays go to
//    scratch (R2/R4 failure).
//
// Shapes: x [65536,256] f32, W_pred [1023,256], b_pred [1023],
//         W_or [16,1024], action_stds [16,1024].
// d_out = [out (65536x16) | std (65536x16)] f32.

#define BATCH   65536
#define IN_DIM  256
#define NLEVEL  10
#define NLEAF   1024
#define OUT_DIM 16
#define EPS_TIE 1e-3f

#define DPP_QUAD_XOR1   0xB1   // quad_perm [1,0,3,2]  : lane ^1
#define DPP_QUAD_XOR2   0x4E   // quad_perm [2,3,0,1]  : lane ^2
#define DPP_HALF_MIRROR 0x141  // row_half_mirror      : lane l <-> 7-l

template <int CTRL>
__device__ __forceinline__ float dpp_xfer(float v) {
    return __int_as_float(__builtin_amdgcn_update_dpp(
        0, __float_as_int(v), CTRL, 0xf, 0xf, true));
}

// Sum across the 8-lane group; bitwise-identical on all 8 lanes
// (involution pairing + commutative add at every step).
__device__ __forceinline__ float group8_sum(float v) {
    v += dpp_xfer<DPP_QUAD_XOR1>(v);
    v += dpp_xfer<DPP_QUAD_XOR2>(v);
    v += dpp_xfer<DPP_HALF_MIRROR>(v);
    return v;
}
__device__ __forceinline__ float group8_max(float v) {
    v = fmaxf(v, dpp_xfer<DPP_QUAD_XOR1>(v));
    v = fmaxf(v, dpp_xfer<DPP_QUAD_XOR2>(v));
    v = fmaxf(v, dpp_xfer<DPP_HALF_MIRROR>(v));
    return v;
}

// Rare exact-sign fallback (|z_f32| < EPS_TIE). Group-uniform entry: z is
// bitwise-uniform across the 8-lane group, so shuffle partners are active.
__device__ __forceinline__ int tree_sign_f64(
    float4 x0, float4 x1, float4 x2, float4 x3,
    float4 x4, float4 x5, float4 x6, float4 x7,
    const float* wrow, float bias, int l)
{
    double A0 = 0.0, A1 = 0.0, A2 = 0.0, A3 = 0.0;
#define ACC64(K, XV)                                                        \
    {                                                                       \
        float4 w = *reinterpret_cast<const float4*>(wrow + (K)*32 + l * 4); \
        A0 += (double)XV.x * (double)w.x; A1 += (double)XV.y * (double)w.y; \
        A2 += (double)XV.z * (double)w.z; A3 += (double)XV.w * (double)w.w; \
    }
    ACC64(0, x0) ACC64(1, x1) ACC64(2, x2) ACC64(3, x3)
    ACC64(4, x4) ACC64(5, x5) ACC64(6, x6) ACC64(7, x7)
#undef ACC64
    double Z = (A0 + A1) + (A2 + A3);
    #pragma unroll
    for (int off = 4; off > 0; off >>= 1)   // xor involution: uniform result
        Z += __shfl_xor(Z, off, 64);
    Z += (double)bias;
    return (Z < 0.0) ? 1 : 0;
}

// 256 threads = 4 waves; 8 samples/wave -> 32/block, 2048 blocks.
__global__ __launch_bounds__(256, 2) void dgt_kernel(
    const float* __restrict__ x,
    const float* __restrict__ W_pred,
    const float* __restrict__ b_pred,
    const float* __restrict__ W_or,
    const float* __restrict__ a_std,
    float* __restrict__ out)
{
    const int lane = threadIdx.x & 63;
    const int wid  = threadIdx.x >> 6;   // wave in block (0..3)
    const int l    = lane & 7;           // lane within 8-group
    const int g    = lane >> 3;          // group (sample) within wave
    const int sample = blockIdx.x * 32 + wid * 8 + g;

    // x fragment: elem k*32 + l*4 + c; 128B coalesced segments per group.
    const float* xrow = x + (size_t)sample * IN_DIM;
    float4 x0 = *reinterpret_cast<const float4*>(xrow +   0 + l * 4);
    float4 x1 = *reinterpret_cast<const float4*>(xrow +  32 + l * 4);
    float4 x2 = *reinterpret_cast<const float4*>(xrow +  64 + l * 4);
    float4 x3 = *reinterpret_cast<const float4*>(xrow +  96 + l * 4);
    float4 x4 = *reinterpret_cast<const float4*>(xrow + 128 + l * 4);
    float4 x5 = *reinterpret_cast<const float4*>(xrow + 160 + l * 4);
    float4 x6 = *reinterpret_cast<const float4*>(xrow + 192 + l * 4);
    float4 x7 = *reinterpret_cast<const float4*>(xrow + 224 + l * 4);

    int node = 0, pos = 0;
    float bcur = b_pred[0];
    const float* wrow = W_pred;

    #pragma unroll
    for (int lvl = 0; lvl < NLEVEL; ++lvl) {
        // All 8 row-fragment loads issued up front: one vmcnt covers them.
        float4 w0 = *reinterpret_cast<const float4*>(wrow +   0 + l * 4);
        float4 w1 = *reinterpret_cast<const float4*>(wrow +  32 + l * 4);
        float4 w2 = *reinterpret_cast<const float4*>(wrow +  64 + l * 4);
        float4 w3 = *reinterpret_cast<const float4*>(wrow +  96 + l * 4);
        float4 w4 = *reinterpret_cast<const float4*>(wrow + 128 + l * 4);
        float4 w5 = *reinterpret_cast<const float4*>(wrow + 160 + l * 4);
        float4 w6 = *reinterpret_cast<const float4*>(wrow + 192 + l * 4);
        float4 w7 = *reinterpret_cast<const float4*>(wrow + 224 + l * 4);

        // Children biases fetched before the sign resolves (off crit path).
        float bL = 0.f, bR = 0.f;
        if (lvl < NLEVEL - 1) {
            bL = b_pred[2 * node + 1];
            bR = b_pred[2 * node + 2];
        }

        // 4 independent partials (8-deep dependent FMA chains each).
        float a0, a1, a2, a3;
        a0  = x0.x * w0.x; a1  = x0.y * w0.y; a2  = x0.z * w0.z; a3  = x0.w * w0.w;
        a0 += x1.x * w1.x; a1 += x1.y * w1.y; a2 += x1.z * w1.z; a3 += x1.w * w1.w;
        a0 += x2.x * w2.x; a1 += x2.y * w2.y; a2 += x2.z * w2.z; a3 += x2.w * w2.w;
        a0 += x3.x * w3.x; a1 += x3.y * w3.y; a2 += x3.z * w3.z; a3 += x3.w * w3.w;
        a0 += x4.x * w4.x; a1 += x4.y * w4.y; a2 += x4.z * w4.z; a3 += x4.w * w4.w;
        a0 += x5.x * w5.x; a1 += x5.y * w5.y; a2 += x5.z * w5.z; a3 += x5.w * w5.w;
        a0 += x6.x * w6.x; a1 += x6.y * w6.y; a2 += x6.z * w6.z; a3 += x6.w * w6.w;
        a0 += x7.x * w7.x; a1 += x7.y * w7.y; a2 += x7.z * w7.z; a3 += x7.w * w7.w;
        float z = group8_sum((a0 + a1) + (a2 + a3)) + bcur;

        int right;
        if (__builtin_expect(fabsf(z) >= EPS_TIE, 1))
            right = (z < 0.f) ? 1 : 0;
        else
            right = tree_sign_f64(x0, x1, x2, x3, x4, x5, x6, x7,
                                  wrow, bcur, l);   // group-uniform entry

        pos  = 2 * pos + right;
        node = 2 * node + 1 + right;
        if (lvl < NLEVEL - 1) {
            bcur = right ? bR : bL;
            wrow = W_pred + (size_t)node * IN_DIM;
        }
    }
    const int leaf = pos;  // in [0, 1024)

    // Epilogue: lane l covers classes {2l, 2l+1}; tables are L2-resident.
    float zx = W_or[(size_t)(2 * l)     * NLEAF + leaf];
    float zy = W_or[(size_t)(2 * l + 1) * NLEAF + leaf];
    float m  = group8_max(fmaxf(zx, zy));
    float ex = __expf(zx - m), ey = __expf(zy - m);
    float s  = group8_sum(ex + ey);
    // Per wave: addresses (base+g)*64B + l*8B -> contiguous 512B.
    *reinterpret_cast<float2*>(out + (size_t)sample * OUT_DIM + 2 * l) =
        make_float2(ex / s, ey / s);

    float dx = a_std[(size_t)(2 * l)     * NLEAF + leaf];
    float dy = a_std[(size_t)(2 * l + 1) * NLEAF + leaf];
    *reinterpret_cast<float2*>(out + (size_t)BATCH * OUT_DIM
                               + (size_t)sample * OUT_DIM + 2 * l) =
        make_float2(fminf(fmaxf(dx, -20.f), 2.f),
                    fminf(fmaxf(dy, -20.f), 2.f));
}

extern "C" void kernel_launch(void* const* d_in, const int* in_sizes, int n_in,
                              void* d_out, int out_size, void* d_ws, size_t ws_size,
                              hipStream_t stream) {
    const float* x      = (const float*)d_in[0];
    const float* W_pred = (const float*)d_in[1];
    const float* b_pred = (const float*)d_in[2];
    const float* W_or   = (const float*)d_in[3];
    const float* a_std  = (const float*)d_in[4];
    float* out = (float*)d_out;

    hipLaunchKernelGGL(dgt_kernel, dim3(BATCH / 32), dim3(256), 0, stream,
                       x, W_pred, b_pred, W_or, a_std, out);
}